// Round 1
// baseline (33.973 us; speedup 1.0000x reference)
//
#include <hip/hip_runtime.h>
#include <math.h>

// ---------------------------------------------------------------------------
// VNFrameEstimator: per batch (B=65536), C=128 3-vectors:
//   v = v_feat / max(||v_feat||, 1e-12)            (per vector)
//   M = sum_c v v^T + diag([1e-5, 2e-5, 3e-5]f32)
//   eigh(M) -> two smallest eigenvectors v1, v2 (ascending eigenvalues)
//   sign-fix v1, v2 against s = sum_c v ; v3 = v1 x v2
//   out[b,i,j] = [v1|v2|v3][i]  (shape B x 3 x 3)
//
// Phase 1: 16 lanes/batch, coalesced float4 loads, f64 accumulate + shfl
// Phase 2: 1 thread/batch 3x3 Jacobi eigensolver in f64 (registers only)
// ---------------------------------------------------------------------------

#define WAVES_PER_BLOCK 4
#define BLOCK (WAVES_PER_BLOCK * 64)
#define ITERS 2
#define BATCHES_PER_WAVE (4 * ITERS)                 // 8
#define BPB (WAVES_PER_BLOCK * BATCHES_PER_WAVE)     // 32 batches per block

// One Jacobi rotation zeroing A[P][Q]; R is the remaining index.
// Template indices => all array accesses compile-time constant => registers.
template <int P, int Q, int R>
__device__ __forceinline__ void jrot(double (&A)[3][3], double (&V)[3][3]) {
    double apq = A[P][Q];
    if (apq != 0.0) {
        double theta = (A[Q][Q] - A[P][P]) / (2.0 * apq);
        double t = 1.0 / (fabs(theta) + sqrt(theta * theta + 1.0));
        if (theta < 0.0) t = -t;
        double c = 1.0 / sqrt(t * t + 1.0);
        double s = t * c;
        double app = A[P][P], aqq = A[Q][Q];
        A[P][P] = app - t * apq;
        A[Q][Q] = aqq + t * apq;
        A[P][Q] = 0.0;
        A[Q][P] = 0.0;
        double apr = A[P][R], aqr = A[Q][R];
        A[P][R] = c * apr - s * aqr; A[R][P] = A[P][R];
        A[Q][R] = s * apr + c * aqr; A[R][Q] = A[Q][R];
#pragma unroll
        for (int i = 0; i < 3; ++i) {
            double vip = V[i][P], viq = V[i][Q];
            V[i][P] = c * vip - s * viq;
            V[i][Q] = s * vip + c * viq;
        }
    }
}

__global__ __launch_bounds__(BLOCK) void vn_frame_kernel(
    const float* __restrict__ vf, float* __restrict__ out, int B) {
    __shared__ double sM[BPB][9];

    const int tid  = threadIdx.x;
    const int wave = tid >> 6;
    const int lane = tid & 63;
    const int g    = lane >> 4;   // which of 4 batches this iter
    const int sub  = lane & 15;   // lane within 16-group

    const int blockBase = blockIdx.x * BPB;

#pragma unroll
    for (int it = 0; it < ITERS; ++it) {
        const int bslot = wave * BATCHES_PER_WAVE + it * 4 + g;
        const int b = blockBase + bslot;
        if (b < B) {
            // 16 lanes x 24 floats = 384 floats = one batch (128 vectors)
            const float4* p4 =
                reinterpret_cast<const float4*>(vf + (size_t)b * 384 + sub * 24);
            float f[24];
#pragma unroll
            for (int i = 0; i < 6; ++i) {
                float4 q = p4[i];
                f[4 * i + 0] = q.x; f[4 * i + 1] = q.y;
                f[4 * i + 2] = q.z; f[4 * i + 3] = q.w;
            }

            double m[9];
#pragma unroll
            for (int k = 0; k < 9; ++k) m[k] = 0.0;

#pragma unroll
            for (int k = 0; k < 8; ++k) {
                double x = (double)f[3 * k + 0];
                double y = (double)f[3 * k + 1];
                double z = (double)f[3 * k + 2];
                double n2 = x * x + y * y + z * z;
                // inv = 1 / max(sqrt(n2), 1e-12); branch exactly at norm==1e-12
                double inv = (n2 > 1e-24) ? rsqrt(n2) : 1e12;
                x *= inv; y *= inv; z *= inv;
                m[0] += x * x; m[1] += x * y; m[2] += x * z;
                m[3] += y * y; m[4] += y * z; m[5] += z * z;
                m[6] += x;     m[7] += y;     m[8] += z;
            }
            // reduce across the 16-lane group
#pragma unroll
            for (int off = 1; off < 16; off <<= 1) {
#pragma unroll
                for (int k = 0; k < 9; ++k) m[k] += __shfl_xor(m[k], off);
            }
            if (sub == 0) {
#pragma unroll
                for (int k = 0; k < 9; ++k) sM[bslot][k] = m[k];
            }
        }
    }

    __syncthreads();

    if (tid < BPB) {
        const int b = blockBase + tid;
        if (b < B) {
            double m[9];
#pragma unroll
            for (int k = 0; k < 9; ++k) m[k] = sM[tid][k];

            double A[3][3], V[3][3];
            A[0][0] = m[0] + (double)1e-05f;
            A[0][1] = m[1]; A[1][0] = m[1];
            A[0][2] = m[2]; A[2][0] = m[2];
            A[1][1] = m[3] + (double)2e-05f;
            A[1][2] = m[4]; A[2][1] = m[4];
            A[2][2] = m[5] + (double)3e-05f;
#pragma unroll
            for (int i = 0; i < 3; ++i)
#pragma unroll
                for (int j = 0; j < 3; ++j) V[i][j] = (i == j) ? 1.0 : 0.0;

#pragma unroll
            for (int sweep = 0; sweep < 6; ++sweep) {
                jrot<0, 1, 2>(A, V);
                jrot<0, 2, 1>(A, V);
                jrot<1, 2, 0>(A, V);
            }

            double e0 = A[0][0], e1 = A[1][1], e2 = A[2][2];
            double c0x = V[0][0], c0y = V[1][0], c0z = V[2][0];
            double c1x = V[0][1], c1y = V[1][1], c1z = V[2][1];
            double c2x = V[0][2], c2y = V[1][2], c2z = V[2][2];

            // sort eigenpairs ascending (3-element swap network)
#define CSWAP(ea, eb, ax, ay, az, bx, by, bz)                         \
            if (ea > eb) {                                            \
                double t_;                                            \
                t_ = ea; ea = eb; eb = t_;                            \
                t_ = ax; ax = bx; bx = t_;                            \
                t_ = ay; ay = by; by = t_;                            \
                t_ = az; az = bz; bz = t_;                            \
            }
            CSWAP(e0, e1, c0x, c0y, c0z, c1x, c1y, c1z)
            CSWAP(e1, e2, c1x, c1y, c1z, c2x, c2y, c2z)
            CSWAP(e0, e1, c0x, c0y, c0z, c1x, c1y, c1z)
#undef CSWAP

            // sign fix: s = sign(dot(sum_v, vec)), sign(0) -> +1
            double s0 = m[6], s1 = m[7], s2 = m[8];
            double d1 = s0 * c0x + s1 * c0y + s2 * c0z;
            double f1 = (d1 < 0.0) ? -1.0 : 1.0;
            c0x *= f1; c0y *= f1; c0z *= f1;
            double d2 = s0 * c1x + s1 * c1y + s2 * c1z;
            double f2 = (d2 < 0.0) ? -1.0 : 1.0;
            c1x *= f2; c1y *= f2; c1z *= f2;

            // v3 = v1 x v2
            double v3x = c0y * c1z - c0z * c1y;
            double v3y = c0z * c1x - c0x * c1z;
            double v3z = c0x * c1y - c0y * c1x;

            float* o = out + (size_t)b * 9;
            o[0] = (float)c0x; o[1] = (float)c1x; o[2] = (float)v3x;
            o[3] = (float)c0y; o[4] = (float)c1y; o[5] = (float)v3y;
            o[6] = (float)c0z; o[7] = (float)c1z; o[8] = (float)v3z;
        }
    }
}

extern "C" void kernel_launch(void* const* d_in, const int* in_sizes, int n_in,
                              void* d_out, int out_size, void* d_ws, size_t ws_size,
                              hipStream_t stream) {
    const float* vf = (const float*)d_in[0];
    float* out = (float*)d_out;
    const int B = in_sizes[0] / 384;  // 128 vectors * 3 components
    const int grid = (B + BPB - 1) / BPB;
    vn_frame_kernel<<<dim3(grid), dim3(BLOCK), 0, stream>>>(vf, out, B);
}

// Round 2
// 28.022 us; speedup vs baseline: 1.2124x; 1.2124x over previous
//
#include <hip/hip_runtime.h>
#include <math.h>

// ---------------------------------------------------------------------------
// VNFrameEstimator: per batch (B=65536), C=128 3-vectors:
//   v = v_feat / max(||v_feat||, 1e-12)            (per vector, f32 norm)
//   M = sum_c v v^T + diag([1e-5, 2e-5, 3e-5]f32)  (f64 accumulate)
//   eigh(M) -> two smallest eigenvectors v1, v2 (ascending eigenvalues)
//   sign-fix v1, v2 against s = sum_c v ; v3 = v1 x v2
//   out[b,:,:] = [v1|v2|v3] columns  (shape B x 3 x 3)
//
// Phase 1: 16 lanes/batch, float4 loads, f32 rsq seed + 1 f64 NR, f64 accum
// Phase 2: 1 thread/batch 3x3 Jacobi in f64, libm-free (NR rcp/rsqrt)
// ---------------------------------------------------------------------------

#define WAVES_PER_BLOCK 4
#define BLOCK (WAVES_PER_BLOCK * 64)
#define ITERS 2
#define BATCHES_PER_WAVE (4 * ITERS)                 // 8
#define BPB (WAVES_PER_BLOCK * BATCHES_PER_WAVE)     // 32 batches per block

// 1/sqrt(x), ~6e-14 rel err. x must be in f32-normal range (guarded by caller).
__device__ __forceinline__ double fast_rsqrt1(double x) {
    double r = (double)__builtin_amdgcn_rsqf((float)x);
    double h = -0.5 * x;
    r = r * fma(h, r * r, 1.5);
    return r;
}
// 1/sqrt(x), ~1e-15 rel err (2 NR steps).
__device__ __forceinline__ double fast_rsqrt2(double x) {
    double r = (double)__builtin_amdgcn_rsqf((float)x);
    double h = -0.5 * x;
    r = r * fma(h, r * r, 1.5);
    r = r * fma(h, r * r, 1.5);
    return r;
}
// 1/x, ~1e-15 rel err (2 NR steps). |x| must be f32-representable (guarded).
__device__ __forceinline__ double fast_rcp(double x) {
    double r = (double)__builtin_amdgcn_rcpf((float)x);
    r = r * fma(-x, r, 2.0);
    r = r * fma(-x, r, 2.0);
    return r;
}

// One Jacobi rotation zeroing A[P][Q]; R is the remaining index.
// Template indices => all array accesses compile-time constant => registers.
template <int P, int Q, int R>
__device__ __forceinline__ void jrot(double (&A)[3][3], double (&V)[3][3]) {
    double apq = A[P][Q];
    if (fabs(apq) > 1e-18) {
        double theta = (A[Q][Q] - A[P][P]) * 0.5 * fast_rcp(apq);
        double q = fma(theta, theta, 1.0);
        double sq = (q < 1e37) ? q * fast_rsqrt2(q) : fabs(theta); // sqrt(q)
        double t = fast_rcp(fabs(theta) + sq);
        if (theta < 0.0) t = -t;
        double c = fast_rsqrt2(fma(t, t, 1.0));
        double s = t * c;
        double apq_t = t * apq;
        A[P][P] = A[P][P] - apq_t;
        A[Q][Q] = A[Q][Q] + apq_t;
        A[P][Q] = 0.0;
        A[Q][P] = 0.0;
        double apr = A[P][R], aqr = A[Q][R];
        A[P][R] = c * apr - s * aqr; A[R][P] = A[P][R];
        A[Q][R] = s * apr + c * aqr; A[R][Q] = A[Q][R];
#pragma unroll
        for (int i = 0; i < 3; ++i) {
            double vip = V[i][P], viq = V[i][Q];
            V[i][P] = c * vip - s * viq;
            V[i][Q] = s * vip + c * viq;
        }
    }
}

__global__ __launch_bounds__(BLOCK) void vn_frame_kernel(
    const float* __restrict__ vf, float* __restrict__ out, int B) {
    __shared__ double sM[BPB][9];

    const int tid  = threadIdx.x;
    const int wave = tid >> 6;
    const int lane = tid & 63;
    const int g    = lane >> 4;   // which of 4 batches this iter
    const int sub  = lane & 15;   // lane within 16-group

    const int blockBase = blockIdx.x * BPB;

#pragma unroll
    for (int it = 0; it < ITERS; ++it) {
        const int bslot = wave * BATCHES_PER_WAVE + it * 4 + g;
        const int b = blockBase + bslot;
        if (b < B) {
            // 16 lanes x 24 floats = 384 floats = one batch (128 vectors)
            const float4* p4 =
                reinterpret_cast<const float4*>(vf + (size_t)b * 384 + sub * 24);
            float f[24];
#pragma unroll
            for (int i = 0; i < 6; ++i) {
                float4 q = p4[i];
                f[4 * i + 0] = q.x; f[4 * i + 1] = q.y;
                f[4 * i + 2] = q.z; f[4 * i + 3] = q.w;
            }

            double m[9];
#pragma unroll
            for (int k = 0; k < 9; ++k) m[k] = 0.0;

#pragma unroll
            for (int k = 0; k < 8; ++k) {
                float fx = f[3 * k + 0];
                float fy = f[3 * k + 1];
                float fz = f[3 * k + 2];
                // n2 in f32 (matches reference's f32 norm computation)
                float n2f = fmaf(fx, fx, fmaf(fy, fy, fz * fz));
                double n2 = (double)n2f;
                // inv = 1/max(sqrt(n2),1e-12); branch exactly at norm==1e-12
                double inv = (n2 > 1e-24) ? fast_rsqrt1(n2) : 1e12;
                double x = (double)fx * inv;
                double y = (double)fy * inv;
                double z = (double)fz * inv;
                m[0] = fma(x, x, m[0]);
                m[1] = fma(x, y, m[1]);
                m[2] = fma(x, z, m[2]);
                m[3] = fma(y, y, m[3]);
                m[4] = fma(y, z, m[4]);
                m[5] = fma(z, z, m[5]);
                m[6] += x; m[7] += y; m[8] += z;
            }
            // reduce across the 16-lane group
#pragma unroll
            for (int off = 1; off < 16; off <<= 1) {
#pragma unroll
                for (int k = 0; k < 9; ++k) m[k] += __shfl_xor(m[k], off);
            }
            if (sub == 0) {
#pragma unroll
                for (int k = 0; k < 9; ++k) sM[bslot][k] = m[k];
            }
        }
    }

    __syncthreads();

    if (tid < BPB) {
        const int b = blockBase + tid;
        if (b < B) {
            double m[9];
#pragma unroll
            for (int k = 0; k < 9; ++k) m[k] = sM[tid][k];

            double A[3][3], V[3][3];
            A[0][0] = m[0] + (double)1e-05f;
            A[0][1] = m[1]; A[1][0] = m[1];
            A[0][2] = m[2]; A[2][0] = m[2];
            A[1][1] = m[3] + (double)2e-05f;
            A[1][2] = m[4]; A[2][1] = m[4];
            A[2][2] = m[5] + (double)3e-05f;
#pragma unroll
            for (int i = 0; i < 3; ++i)
#pragma unroll
                for (int j = 0; j < 3; ++j) V[i][j] = (i == j) ? 1.0 : 0.0;

#pragma unroll
            for (int sweep = 0; sweep < 6; ++sweep) {
                jrot<0, 1, 2>(A, V);
                jrot<0, 2, 1>(A, V);
                jrot<1, 2, 0>(A, V);
            }

            double e0 = A[0][0], e1 = A[1][1], e2 = A[2][2];
            double c0x = V[0][0], c0y = V[1][0], c0z = V[2][0];
            double c1x = V[0][1], c1y = V[1][1], c1z = V[2][1];
            double c2x = V[0][2], c2y = V[1][2], c2z = V[2][2];

            // sort eigenpairs ascending (3-element swap network)
#define CSWAP(ea, eb, ax, ay, az, bx, by, bz)                         \
            if (ea > eb) {                                            \
                double t_;                                            \
                t_ = ea; ea = eb; eb = t_;                            \
                t_ = ax; ax = bx; bx = t_;                            \
                t_ = ay; ay = by; by = t_;                            \
                t_ = az; az = bz; bz = t_;                            \
            }
            CSWAP(e0, e1, c0x, c0y, c0z, c1x, c1y, c1z)
            CSWAP(e1, e2, c1x, c1y, c1z, c2x, c2y, c2z)
            CSWAP(e0, e1, c0x, c0y, c0z, c1x, c1y, c1z)
#undef CSWAP

            // sign fix: s = sign(dot(sum_v, vec)), sign(0) -> +1
            double s0 = m[6], s1 = m[7], s2 = m[8];
            double d1 = s0 * c0x + s1 * c0y + s2 * c0z;
            double f1 = (d1 < 0.0) ? -1.0 : 1.0;
            c0x *= f1; c0y *= f1; c0z *= f1;
            double d2 = s0 * c1x + s1 * c1y + s2 * c1z;
            double f2 = (d2 < 0.0) ? -1.0 : 1.0;
            c1x *= f2; c1y *= f2; c1z *= f2;

            // v3 = v1 x v2
            double v3x = c0y * c1z - c0z * c1y;
            double v3y = c0z * c1x - c0x * c1z;
            double v3z = c0x * c1y - c0y * c1x;

            float* o = out + (size_t)b * 9;
            o[0] = (float)c0x; o[1] = (float)c1x; o[2] = (float)v3x;
            o[3] = (float)c0y; o[4] = (float)c1y; o[5] = (float)v3y;
            o[6] = (float)c0z; o[7] = (float)c1z; o[8] = (float)v3z;
        }
    }
}

extern "C" void kernel_launch(void* const* d_in, const int* in_sizes, int n_in,
                              void* d_out, int out_size, void* d_ws, size_t ws_size,
                              hipStream_t stream) {
    const float* vf = (const float*)d_in[0];
    float* out = (float*)d_out;
    const int B = in_sizes[0] / 384;  // 128 vectors * 3 components
    const int grid = (B + BPB - 1) / BPB;
    vn_frame_kernel<<<dim3(grid), dim3(BLOCK), 0, stream>>>(vf, out, B);
}